// Round 1
// baseline (995.022 us; speedup 1.0000x reference)
//
#include <hip/hip_runtime.h>
#include <math.h>

// KAN activation: out = wb * silu(x) + ws * BSpline(knots, coeffs, k=3)(x)
// knots = linspace(-5,5,10) (but handled generically), n = 10-3-1 = 6 active
// coeffs. Interval index i = clip(searchsorted(t,x,'right')-1, 3, 5), so only
// three de Boor variants exist -> fully branchless via cndmask selects.

__global__ __launch_bounds__(256) void kan_kernel(
    const float* __restrict__ xin,
    const float* __restrict__ knots,
    const float* __restrict__ coeffs,
    const float* __restrict__ wbp,
    const float* __restrict__ wsp,
    float* __restrict__ out,
    long long n)
{
    // Uniform preloads (compiler emits scalar loads; values live in SGPRs).
    const float t1 = knots[1], t2 = knots[2], t3 = knots[3], t4 = knots[4];
    const float t5 = knots[5], t6 = knots[6], t7 = knots[7], t8 = knots[8];
    const float c0 = coeffs[0], c1 = coeffs[1], c2 = coeffs[2];
    const float c3 = coeffs[3], c4 = coeffs[4], c5 = coeffs[5];
    const float wb = wbp[0], ws = wsp[0];

    // Inverse denominators per interval i in {3,4,5} (index = i-3).
    // r=1: spans of 3 knots; r=2: spans of 2; r=3: spans of 1.
    // Hoisted out of the hot loop: 12 distinct precise divisions per thread,
    // amortized over ~64 elements.
    const float i13_0 = 1.0f / (t6 - t3), i13_1 = 1.0f / (t7 - t4), i13_2 = 1.0f / (t8 - t5);
    const float i12_0 = 1.0f / (t5 - t2), i12_1 = 1.0f / (t6 - t3), i12_2 = 1.0f / (t7 - t4);
    const float i11_0 = 1.0f / (t4 - t1), i11_1 = 1.0f / (t5 - t2), i11_2 = 1.0f / (t6 - t3);
    const float i23_0 = 1.0f / (t5 - t3), i23_1 = 1.0f / (t6 - t4), i23_2 = 1.0f / (t7 - t5);
    const float i22_0 = 1.0f / (t4 - t2), i22_1 = 1.0f / (t5 - t3), i22_2 = 1.0f / (t6 - t4);
    const float i33_0 = 1.0f / (t4 - t3), i33_1 = 1.0f / (t5 - t4), i33_2 = 1.0f / (t6 - t5);

    auto eval = [&](float x) -> float {
        const bool ge4 = (x >= t4);   // i >= 4
        const bool ge5 = (x >= t5);   // i == 5
#define KAN_SEL(a, b, c) (ge4 ? (ge5 ? (c) : (b)) : (a))
        // de Boor working set d[j] = c[i-3+j]
        float d0 = KAN_SEL(c0, c1, c2);
        float d1 = KAN_SEL(c1, c2, c3);
        float d2 = KAN_SEL(c2, c3, c4);
        float d3 = KAN_SEL(c3, c4, c5);
        // knots t[i], t[i-1], t[i-2] (the only t_lo values needed)
        const float ti   = KAN_SEL(t3, t4, t5);
        const float tim1 = KAN_SEL(t2, t3, t4);
        const float tim2 = KAN_SEL(t1, t2, t3);
        // inverse denominators for this interval
        const float i13 = KAN_SEL(i13_0, i13_1, i13_2);
        const float i12 = KAN_SEL(i12_0, i12_1, i12_2);
        const float i11 = KAN_SEL(i11_0, i11_1, i11_2);
        const float i23 = KAN_SEL(i23_0, i23_1, i23_2);
        const float i22 = KAN_SEL(i22_0, i22_1, i22_2);
        const float i33 = KAN_SEL(i33_0, i33_1, i33_2);
#undef KAN_SEL
        const float u0 = x - ti;     // x - t[i]
        const float u1 = x - tim1;   // x - t[i-1]
        const float u2 = x - tim2;   // x - t[i-2]
        float a;
        // r = 1 (j = 3,2,1): d[j] = d[j-1] + alpha*(d[j] - d[j-1])
        a = u0 * i13; d3 = fmaf(a, d3 - d2, d2);
        a = u1 * i12; d2 = fmaf(a, d2 - d1, d1);
        a = u2 * i11; d1 = fmaf(a, d1 - d0, d0);
        // r = 2 (j = 3,2)
        a = u0 * i23; d3 = fmaf(a, d3 - d2, d2);
        a = u1 * i22; d2 = fmaf(a, d2 - d1, d1);
        // r = 3 (j = 3)
        a = u0 * i33; d3 = fmaf(a, d3 - d2, d2);
        // silu(x) = x / (1 + exp(-x)) via hw exp + hw rcp (~2 ulp)
        const float e = __expf(-x);
        const float b = x * __builtin_amdgcn_rcpf(1.0f + e);
        return fmaf(wb, b, ws * d3);
    };

    const long long tid    = (long long)blockIdx.x * blockDim.x + threadIdx.x;
    const long long stride = (long long)gridDim.x * blockDim.x;
    const long long n4 = n >> 2;

    const float4* __restrict__ x4 = (const float4*)xin;
    float4* __restrict__ o4 = (float4*)out;
    for (long long v = tid; v < n4; v += stride) {
        const float4 xv = x4[v];
        float4 ov;
        ov.x = eval(xv.x);
        ov.y = eval(xv.y);
        ov.z = eval(xv.z);
        ov.w = eval(xv.w);
        o4[v] = ov;
    }
    // tail (n is divisible by 4 for this problem, but stay generic)
    for (long long j = (n4 << 2) + tid; j < n; j += stride) {
        out[j] = eval(xin[j]);
    }
}

extern "C" void kernel_launch(void* const* d_in, const int* in_sizes, int n_in,
                              void* d_out, int out_size, void* d_ws, size_t ws_size,
                              hipStream_t stream) {
    const float* x      = (const float*)d_in[0];
    const float* knots  = (const float*)d_in[1];
    const float* coeffs = (const float*)d_in[2];
    const float* wb     = (const float*)d_in[3];
    const float* ws     = (const float*)d_in[4];
    float* out = (float*)d_out;

    const long long n = (long long)out_size;
    const int block = 256;
    const int grid  = 2048;  // grid-stride; ~16 float4 iters/thread at n=33.5M
    kan_kernel<<<grid, block, 0, stream>>>(x, knots, coeffs, wb, ws, out, n);
}